// Round 1
// baseline (577.027 us; speedup 1.0000x reference)
//
#include <hip/hip_runtime.h>

#define D_FEAT 128
#define ALPHA_ 0.1f

__global__ void k_wsum(const int* __restrict__ row, const float* __restrict__ w,
                       float* __restrict__ ws, int E) {
    int e = blockIdx.x * blockDim.x + threadIdx.x;
    if (e < E) atomicAdd(&ws[row[e]], w[e]);
}

__global__ void k_init_out(const float4* __restrict__ x4, float4* __restrict__ out4, int n4) {
    int i = blockIdx.x * blockDim.x + threadIdx.x;
    if (i < n4) {
        float4 v = x4[i];
        out4[i] = make_float4(ALPHA_ * v.x, ALPHA_ * v.y, ALPHA_ * v.z, ALPHA_ * v.w);
    }
}

// One 64-lane wave per edge; each lane handles 2 features (float2).
__global__ void k_scatter(const int* __restrict__ row, const int* __restrict__ col,
                          const float* __restrict__ w, const float* __restrict__ ws,
                          const float* __restrict__ x, float* __restrict__ out, int E) {
    int gid = blockIdx.x * blockDim.x + threadIdx.x;
    int e = gid >> 6;
    if (e >= E) return;
    int lane = threadIdx.x & 63;

    int r = row[e];
    int c = col[e];
    float norm = (1.0f - ALPHA_) * w[e] / fmaxf(ws[r], 1.0f);

    float2 v = *(const float2*)(x + (size_t)r * D_FEAT + lane * 2);
    float* o = out + (size_t)c * D_FEAT + lane * 2;
    atomicAdd(o + 0, v.x * norm);
    atomicAdd(o + 1, v.y * norm);
}

extern "C" void kernel_launch(void* const* d_in, const int* in_sizes, int n_in,
                              void* d_out, int out_size, void* d_ws, size_t ws_size,
                              hipStream_t stream) {
    const float* x  = (const float*)d_in[0];
    const int*   ei = (const int*)d_in[1];
    const float* ew = (const float*)d_in[2];
    int E = in_sizes[2];
    int N = in_sizes[0] / D_FEAT;
    const int* row = ei;
    const int* col = ei + E;

    float* ws  = (float*)d_ws;   // N floats of scratch for weight sums
    float* out = (float*)d_out;

    // weight_sum must be zeroed every call (harness doesn't re-poison between replays)
    hipMemsetAsync(ws, 0, (size_t)N * sizeof(float), stream);

    k_wsum<<<(E + 255) / 256, 256, 0, stream>>>(row, ew, ws, E);

    int n4 = (N * D_FEAT) / 4;
    k_init_out<<<(n4 + 255) / 256, 256, 0, stream>>>((const float4*)x, (float4*)out, n4);

    long long total = (long long)E * 64;
    int blocks = (int)((total + 255) / 256);
    k_scatter<<<blocks, 256, 0, stream>>>(row, col, ew, ws, x, out, E);
}

// Round 2
// 159.945 us; speedup vs baseline: 3.6077x; 3.6077x over previous
//
#include <hip/hip_runtime.h>
#include <stdint.h>

#define D_FEAT 128
#define ALPHA_ 0.1f
#define SCANB 1024
#define TILE 128

// ---------- CSC path ----------

// fused: weighted out-degree (by row) + in-degree histogram (by col)
__global__ void k_edge_pass1(const int* __restrict__ row, const int* __restrict__ col,
                             const float* __restrict__ w,
                             float* __restrict__ ws, int* __restrict__ hist, int E) {
    int e = blockIdx.x * blockDim.x + threadIdx.x;
    if (e < E) {
        atomicAdd(&ws[row[e]], w[e]);
        atomicAdd(&hist[col[e]], 1);
    }
}

// single-block exclusive scan of hist[0..N) -> start[0..N], cursor copy
__global__ void k_scan(const int* __restrict__ hist, int* __restrict__ start,
                       int* __restrict__ cursor, int N) {
    __shared__ int lds[SCANB];
    int t = threadIdx.x;
    int CH = (N + SCANB - 1) / SCANB;
    int lo = t * CH, hi = min(lo + CH, N);
    int s = 0;
    for (int i = lo; i < hi; i++) s += hist[i];
    lds[t] = s;
    __syncthreads();
    for (int off = 1; off < SCANB; off <<= 1) {
        int v = (t >= off) ? lds[t - off] : 0;
        __syncthreads();
        lds[t] += v;
        __syncthreads();
    }
    int run = lds[t] - s;   // exclusive prefix of this chunk
    for (int i = lo; i < hi; i++) {
        start[i] = run; cursor[i] = run; run += hist[i];
    }
    if (t == SCANB - 1) start[N] = run;   // == E
}

// place each edge's (row, premultiplied norm) into its column bucket
__global__ void k_build(const int* __restrict__ row, const int* __restrict__ col,
                        const float* __restrict__ w, const float* __restrict__ ws,
                        int* __restrict__ cursor, int2* __restrict__ rec, int E) {
    int e = blockIdx.x * blockDim.x + threadIdx.x;
    if (e < E) {
        int c = col[e], r = row[e];
        float norm = (1.0f - ALPHA_) * w[e] / fmaxf(ws[r], 1.0f);
        int pos = atomicAdd(&cursor[c], 1);
        rec[pos] = make_int2(r, __float_as_int(norm));
    }
}

// one block per destination node, one thread per feature; atomic-free
__global__ void k_gather(const int* __restrict__ start, const int2* __restrict__ rec,
                         const float* __restrict__ x, float* __restrict__ out, int N) {
    int c = blockIdx.x;
    int f = threadIdx.x;
    int s = start[c], e = start[c + 1];
    float acc = ALPHA_ * x[(size_t)c * D_FEAT + f];
    __shared__ int2 lds[TILE];
    for (int base = s; base < e; base += TILE) {
        int n = min(TILE, e - base);
        if (f < n) lds[f] = rec[base + f];
        __syncthreads();
        #pragma unroll 4
        for (int i = 0; i < n; i++) {
            int2 rc = lds[i];
            acc += __int_as_float(rc.y) * x[(size_t)rc.x * D_FEAT + f];
        }
        __syncthreads();
    }
    out[(size_t)c * D_FEAT + f] = acc;
}

// ---------- fallback (R0 atomic path), used only if ws_size too small ----------

__global__ void k_wsum(const int* __restrict__ row, const float* __restrict__ w,
                       float* __restrict__ ws, int E) {
    int e = blockIdx.x * blockDim.x + threadIdx.x;
    if (e < E) atomicAdd(&ws[row[e]], w[e]);
}

__global__ void k_init_out(const float4* __restrict__ x4, float4* __restrict__ out4, int n4) {
    int i = blockIdx.x * blockDim.x + threadIdx.x;
    if (i < n4) {
        float4 v = x4[i];
        out4[i] = make_float4(ALPHA_ * v.x, ALPHA_ * v.y, ALPHA_ * v.z, ALPHA_ * v.w);
    }
}

__global__ void k_scatter(const int* __restrict__ row, const int* __restrict__ col,
                          const float* __restrict__ w, const float* __restrict__ ws,
                          const float* __restrict__ x, float* __restrict__ out, int E) {
    int gid = blockIdx.x * blockDim.x + threadIdx.x;
    int e = gid >> 6;
    if (e >= E) return;
    int lane = threadIdx.x & 63;
    int r = row[e];
    int c = col[e];
    float norm = (1.0f - ALPHA_) * w[e] / fmaxf(ws[r], 1.0f);
    float2 v = *(const float2*)(x + (size_t)r * D_FEAT + lane * 2);
    float* o = out + (size_t)c * D_FEAT + lane * 2;
    atomicAdd(o + 0, v.x * norm);
    atomicAdd(o + 1, v.y * norm);
}

extern "C" void kernel_launch(void* const* d_in, const int* in_sizes, int n_in,
                              void* d_out, int out_size, void* d_ws, size_t ws_size,
                              hipStream_t stream) {
    const float* x  = (const float*)d_in[0];
    const int*   ei = (const int*)d_in[1];
    const float* ew = (const float*)d_in[2];
    int E = in_sizes[2];
    int N = in_sizes[0] / D_FEAT;
    const int* row = ei;
    const int* col = ei + E;
    float* out = (float*)d_out;

    // ws layout
    float* wsf   = (float*)d_ws;                  // N floats
    int*   hist  = (int*)(wsf + N);               // N
    int*   startp= hist + N;                      // N+1
    int*   cursor= startp + N + 1;                // N
    uintptr_t rec_addr = ((uintptr_t)(cursor + N) + 15) & ~(uintptr_t)15;
    int2*  rec   = (int2*)rec_addr;               // E records
    size_t need  = (rec_addr - (uintptr_t)d_ws) + (size_t)E * sizeof(int2);

    if (ws_size >= need) {
        // zero ws + hist (contiguous 2N words)
        hipMemsetAsync(d_ws, 0, (size_t)2 * N * sizeof(int), stream);
        int eb = (E + 255) / 256;
        k_edge_pass1<<<eb, 256, 0, stream>>>(row, col, ew, wsf, hist, E);
        k_scan<<<1, SCANB, 0, stream>>>(hist, startp, cursor, N);
        k_build<<<eb, 256, 0, stream>>>(row, col, ew, wsf, cursor, rec, E);
        k_gather<<<N, D_FEAT, 0, stream>>>(startp, rec, x, out, N);
    } else {
        // fallback: atomic scatter (needs only N floats of ws)
        hipMemsetAsync(wsf, 0, (size_t)N * sizeof(float), stream);
        k_wsum<<<(E + 255) / 256, 256, 0, stream>>>(row, ew, wsf, E);
        int n4 = (N * D_FEAT) / 4;
        k_init_out<<<(n4 + 255) / 256, 256, 0, stream>>>((const float4*)x, (float4*)out, n4);
        long long total = (long long)E * 64;
        int blocks = (int)((total + 255) / 256);
        k_scatter<<<blocks, 256, 0, stream>>>(row, col, ew, wsf, x, out, E);
    }
}